// Round 7
// baseline (1281.470 us; speedup 1.0000x reference)
//
#include <hip/hip_runtime.h>
#include <math.h>

#define HH 480
#define WW 600
#define NN (HH*WW)      // 288000
#define PP 2048
#define H2 240
#define W2 300
#define N2 (H2*W2)      // 72000

typedef __bf16  bf16x8  __attribute__((ext_vector_type(8)));
typedef float   f32x4   __attribute__((ext_vector_type(4)));
typedef ushort  ushort8 __attribute__((ext_vector_type(8)));

__device__ __forceinline__ ushort f2b(float f) {
    unsigned u = __float_as_uint(f);
    unsigned r = (u + 0x7FFF + ((u >> 16) & 1)) >> 16;
    return (ushort)r;
}
__device__ __forceinline__ float b2f(ushort u) {
    return __uint_as_float(((unsigned)u) << 16);
}

// ---- workspace layout (bytes) ----
// raw (un-normalized) conv outputs stored bf16 [px][C]; GN applied at consumer.
constexpr size_t alup(size_t x) { return (x + 4095) & ~(size_t)4095; }
constexpr size_t OFF_X    = 4096;                          // 3*NN f32 planar
constexpr size_t OFF_C1R  = alup(OFF_X   + 3UL*NN*4);      // NN*32 bf16 raw conv1
constexpr size_t OFF_RW2  = alup(OFF_C1R + 32UL*NN*2);     // N2*64 bf16 raw conv2
constexpr size_t OFF_RW3  = alup(OFF_RW2 + 64UL*N2*2);     // N2*64 bf16 raw conv3
constexpr size_t OFF_WB2  = alup(OFF_RW3 + 64UL*N2*2);     // 9*64*32 bf16
constexpr size_t OFF_WB3  = alup(OFF_WB2 + 36864UL);       // 9*2*64*32 bf16
constexpr size_t OFF_WB4  = alup(OFF_WB3 + 73728UL);       // 9*3*64*32 bf16
constexpr size_t OFF_SLOT = alup(OFF_WB4 + 110592UL);      // NN int
constexpr size_t OFF_CMP  = alup(OFF_SLOT + (size_t)NN*4); // PP*64 f32 compact conv4 rows

// ---------------- depth mean ----------------
__global__ void k_sum(const float* __restrict__ d, float* __restrict__ ws) {
    float s = 0.f;
    for (int i = blockIdx.x*blockDim.x + threadIdx.x; i < NN; i += gridDim.x*blockDim.x)
        s += d[i];
    #pragma unroll
    for (int o = 32; o; o >>= 1) s += __shfl_down(s, o, 64);
    __shared__ float sm[4];
    int wid = threadIdx.x >> 6;
    if ((threadIdx.x & 63) == 0) sm[wid] = s;
    __syncthreads();
    if (threadIdx.x == 0) {
        float t = 0.f;
        for (int w = 0; w < (int)(blockDim.x >> 6); ++w) t += sm[w];
        atomicAdd(ws, t);
    }
}

__global__ void k_buildx(const float* __restrict__ depth, const float* __restrict__ mask,
                         const float* __restrict__ ws, float* __restrict__ x) {
    int i = blockIdx.x*blockDim.x + threadIdx.x;
    if (i >= NN) return;
    float mean = ws[0] * (1.0f/NN);
    x[i]        = (depth[i] - mean) * 10.0f;
    x[NN + i]   = mask[i];
    x[2*NN + i] = 0.f;
}

__global__ void k_scatter(const int* __restrict__ pairs, float* __restrict__ x) {
    int p = blockIdx.x*blockDim.x + threadIdx.x;
    if (p < PP) x[2*NN + pairs[2*p]] = 1.0f;
}

__global__ void k_slot(const int* __restrict__ pairs, int* __restrict__ slotmap) {
    int p = blockIdx.x*blockDim.x + threadIdx.x;
    if (p < PP) slotmap[pairs[2*p]] = p;
}

// ------------- weight pre-transform to MFMA A-fragment layout (bf16) -------------
// dst[((t*NCH + c)*64 + co)*32 + k] = w[co][c*32+k][t]   (t = ky*3+kx)
__global__ void k_wcvt(const float* __restrict__ w, ushort* __restrict__ dst, int NCH) {
    int e = blockIdx.x*256 + threadIdx.x;
    int total = 9*NCH*64*32;
    if (e >= total) return;
    int k  = e & 31;
    int co = (e >> 5) & 63;
    int rest = e >> 11;
    int c = rest % NCH;
    int t = rest / NCH;
    dst[e] = f2b(w[(co*(NCH*32) + c*32 + k)*9 + t]);
}

// ------- conv1: direct 3x3, 3ch fp32 planar -> raw bf16 [px][32] + fused GN1 stats -------
template<int CIN, int TCO>
__global__ __launch_bounds__(64) void k_conv1(const float* __restrict__ in,
        const float* __restrict__ w, const float* __restrict__ bias,
        ushort* __restrict__ outb, float* __restrict__ stat) {
    int x   = blockIdx.x*64 + threadIdx.x;
    int y   = blockIdx.y;
    int co0 = blockIdx.z*TCO;
    bool valid = x < WW;
    float acc[TCO];
    #pragma unroll
    for (int c = 0; c < TCO; ++c) acc[c] = bias[co0+c];
    if (valid) {
        int  xb   = x - 1;
        bool xint = (xb >= 0) && (xb + 2 < WW);
        for (int ci = 0; ci < CIN; ++ci) {
            const float* ip = in + (long)ci*NN;
            float iv[3][3];
            #pragma unroll
            for (int dy = 0; dy < 3; ++dy) {
                int iy = y + dy - 1;
                if ((unsigned)iy < (unsigned)HH) {
                    const float* rp = ip + (long)iy*WW + xb;
                    if (xint) { iv[dy][0]=rp[0]; iv[dy][1]=rp[1]; iv[dy][2]=rp[2]; }
                    else {
                        #pragma unroll
                        for (int dx = 0; dx < 3; ++dx) {
                            int ix = xb + dx;
                            iv[dy][dx] = ((unsigned)ix < (unsigned)WW) ? ip[(long)iy*WW+ix] : 0.f;
                        }
                    }
                } else iv[dy][0]=iv[dy][1]=iv[dy][2]=0.f;
            }
            const float* wp = w + ((long)co0*CIN + ci)*9;
            #pragma unroll
            for (int c = 0; c < TCO; ++c)
                #pragma unroll
                for (int k = 0; k < 9; ++k)
                    acc[c] += iv[k/3][k%3] * wp[(long)c*CIN*9 + k];
        }
        ushort8 p0, p1;
        #pragma unroll
        for (int j = 0; j < 8; ++j) { p0[j] = f2b(acc[j]); p1[j] = f2b(acc[8+j]); }
        ushort* op = outb + (size_t)(y*WW + x)*32 + co0;
        *(ushort8*)op     = p0;
        *(ushort8*)(op+8) = p1;
    }
    // fused GN1 stats (chper=2): per-thread 8 group partials over 16 channels
    float s[TCO/2], s2[TCO/2];
    #pragma unroll
    for (int j = 0; j < TCO/2; ++j) {
        float a = valid ? acc[2*j]   : 0.f;
        float b = valid ? acc[2*j+1] : 0.f;
        s[j] = a + b; s2[j] = a*a + b*b;
    }
    #pragma unroll
    for (int o = 1; o < 64; o <<= 1)
        #pragma unroll
        for (int j = 0; j < TCO/2; ++j) {
            s[j]  += __shfl_xor(s[j],  o, 64);
            s2[j] += __shfl_xor(s2[j], o, 64);
        }
    if (threadIdx.x == 0) {
        #pragma unroll
        for (int j = 0; j < TCO/2; ++j) {
            int g = (co0 >> 1) + j;
            atomicAdd(&stat[g],    s[j]);
            atomicAdd(&stat[16+g], s2[j]);
        }
    }
}

// ---------------- LDS-staged MFMA implicit-GEMM 3x3 conv, GN-on-stage ----------------
// Inputs are RAW bf16 [px][C]; staging applies GN (A,B per channel from stats) + lrelu.
// MODE 2: conv2 32->64 s2 (C1 raw -> RW2 raw + st2), tile 4x32
// MODE 3: conv3 64->64    (RW2 raw -> RW3 raw + st3), tile 4x64
// MODE 4: conv4 96->64    (up2x(RW3) ++ C1 raw -> compact rows only + st4), tile 4x64
template<int MODE>
__global__ __launch_bounds__(256) void k_sconv(
        const ushort* __restrict__ inA, const ushort* __restrict__ inB,
        const ushort* __restrict__ wb, const float* __restrict__ bias,
        const float* __restrict__ gsA, const float* __restrict__ gbA, const float* __restrict__ stA,
        const float* __restrict__ gsB, const float* __restrict__ gbB, const float* __restrict__ stB,
        ushort* __restrict__ outb,
        const int* __restrict__ slotmap, float* __restrict__ compact,
        float* __restrict__ stat) {
    constexpr int Wo   = (MODE==4) ? WW : W2;
    constexpr int NCH  = (MODE==2) ? 1 : (MODE==3) ? 2 : 3;
    constexpr int NPT  = (MODE==2) ? 2 : 4;
    constexpr int ROWS = (MODE==2) ? 9 : 6;
    constexpr int PXS  = 68;
    constexpr int CPITCH = 36;
    constexpr int UNITS = ROWS*PXS*4;
    constexpr int Hi = (MODE==3) ? H2 : HH;
    constexpr int Wi = (MODE==3) ? W2 : WW;
    __shared__ __align__(16) ushort sh[ROWS*PXS*CPITCH];
    __shared__ float sred[4][16][2];

    int w    = threadIdx.x >> 6;
    int lane = threadIdx.x & 63;
    int lm   = lane & 15;
    int lg   = lane >> 4;
    int q    = threadIdx.x & 3;           // fixed ci-octet per thread
    int y0   = blockIdx.y*4;
    int x0   = blockIdx.x*(NPT*16);
    int y    = y0 + w;
    int iy0  = (MODE==2) ? 2*y0 : y0 - 1;
    int ix0  = (MODE==2) ? 2*x0 : x0 - 1;

    f32x4 acc[4][NPT];
    #pragma unroll
    for (int ct = 0; ct < 4; ++ct)
        #pragma unroll
        for (int pt = 0; pt < NPT; ++pt) acc[ct][pt] = 0.f;

    int dsbase = (((MODE==2 ? 2*w*PXS + 2*lm : w*PXS + lm))*CPITCH + lg*8);

    #pragma unroll
    for (int kc = 0; kc < NCH; ++kc) {
        if (kc) __syncthreads();
        // ---- per-chunk GN coefficients for this thread's 8 channels ----
        float Ac[8], Bc[8];
        {
            const bool useB = (MODE==4) && (kc == 2);
            const float* gs = useB ? gsB : gsA;
            const float* gb = useB ? gbB : gbA;
            const float* st = useB ? stB : stA;
            const float cnt = (MODE==2 || useB) ? 2.0f*(float)NN : 4.0f*(float)N2;
            const int   shp = (MODE==2 || useB) ? 1 : 2;
            const int   cb  = (MODE==2 || useB) ? q*8 : kc*32 + q*8;
            #pragma unroll
            for (int j = 0; j < 8; ++j) {
                int c = cb + j, g = c >> shp;
                float mu  = st[g] / cnt;
                float var = st[16+g] / cnt - mu*mu;
                float rs  = rsqrtf(var + 1e-5f);
                float a   = rs * gs[c];
                Ac[j] = a; Bc[j] = gb[c] - mu*a;
            }
        }
        // ---- stage chunk kc (raw bf16 -> GN+lrelu -> bf16 LDS) ----
        #pragma unroll
        for (int u0 = 0; u0 < UNITS; u0 += 256) {
            int u = u0 + threadIdx.x;
            if (u < UNITS) {
                int r  = u / (PXS*4);
                int rm = u - r*(PXS*4);
                int px = rm >> 2;
                int iy = iy0 + r;
                int ix = ix0 + px;
                ushort8 pk = {};
                if ((unsigned)iy < (unsigned)Hi && (unsigned)ix < (unsigned)Wi) {
                    const ushort* sp;
                    if (MODE==2)      sp = inA + ((size_t)iy*WW + ix)*32 + q*8;
                    else if (MODE==3) sp = inA + ((size_t)iy*W2 + ix)*64 + kc*32 + q*8;
                    else if (kc < 2)  sp = inA + ((size_t)(iy>>1)*W2 + (ix>>1))*64 + kc*32 + q*8;
                    else              sp = inB + ((size_t)iy*WW + ix)*32 + q*8;
                    ushort8 raw = *(const ushort8*)sp;
                    #pragma unroll
                    for (int j = 0; j < 8; ++j) {
                        float t = b2f(raw[j])*Ac[j] + Bc[j];
                        pk[j] = f2b(t >= 0.f ? t : 0.2f*t);
                    }
                }
                *(ushort8*)&sh[(r*PXS + px)*CPITCH + q*8] = pk;
            }
        }
        __syncthreads();
        // ---- compute chunk kc ----
        #pragma unroll
        for (int t = 0; t < 9; ++t) {
            const int dy = t/3, dx = t - 3*(t/3);
            const ushort* wp = wb + (size_t)((t*NCH + kc)*64)*32;
            bf16x8 a[4];
            #pragma unroll
            for (int ct = 0; ct < 4; ++ct)
                a[ct] = *(const bf16x8*)(wp + (ct*16 + lm)*32 + lg*8);
            #pragma unroll
            for (int pt = 0; pt < NPT; ++pt) {
                int off = (dy*PXS + (MODE==2 ? pt*32 + dx : pt*16 + dx))*CPITCH;
                bf16x8 b = *(const bf16x8*)&sh[dsbase + off];
                #pragma unroll
                for (int ct = 0; ct < 4; ++ct)
                    acc[ct][pt] = __builtin_amdgcn_mfma_f32_16x16x32_bf16(a[ct], b, acc[ct][pt], 0, 0, 0);
            }
        }
    }

    // ---- epilogue ----
    if (MODE != 4) {
        // raw bf16 store [px][64] + fused GN stats (chper=4: group = ct*4+lg)
        #pragma unroll
        for (int ct = 0; ct < 4; ++ct) {
            float s = 0.f, s2 = 0.f;
            #pragma unroll
            for (int pt = 0; pt < NPT; ++pt) {
                int pxg = x0 + pt*16 + lm;
                bool vld = pxg < Wo;
                ushort4 pk;
                #pragma unroll
                for (int reg = 0; reg < 4; ++reg) {
                    int co = ct*16 + lg*4 + reg;
                    float v = acc[ct][pt][reg] + bias[co];
                    ((ushort*)&pk)[reg] = f2b(v);
                    if (vld) { s += v; s2 += v*v; }
                }
                if (vld)
                    *(ushort4*)(outb + (size_t)(y*Wo + pxg)*64 + ct*16 + lg*4) = pk;
            }
            #pragma unroll
            for (int o = 1; o < 16; o <<= 1) {
                s  += __shfl_xor(s,  o, 64);
                s2 += __shfl_xor(s2, o, 64);
            }
            if (lm == 0) { sred[w][ct*4+lg][0] = s; sred[w][ct*4+lg][1] = s2; }
        }
    } else {
        // stats over all px + sparse compact-row store for gathered pixels
        int slots[4];
        #pragma unroll
        for (int pt = 0; pt < 4; ++pt) {
            int pxg = x0 + pt*16 + lm;
            slots[pt] = (pxg < Wo) ? slotmap[(size_t)y*Wo + pxg] : -1;
        }
        #pragma unroll
        for (int ct = 0; ct < 4; ++ct) {
            float s = 0.f, s2 = 0.f;
            #pragma unroll
            for (int pt = 0; pt < 4; ++pt) {
                int pxg = x0 + pt*16 + lm;
                bool vld = pxg < Wo;
                f32x4 r;
                #pragma unroll
                for (int reg = 0; reg < 4; ++reg) {
                    int co = ct*16 + lg*4 + reg;
                    float v = acc[ct][pt][reg] + bias[co];
                    r[reg] = v;
                    if (vld) { s += v; s2 += v*v; }
                }
                if (slots[pt] >= 0)
                    *(f32x4*)(compact + (size_t)slots[pt]*64 + ct*16 + lg*4) = r;
            }
            #pragma unroll
            for (int o = 1; o < 16; o <<= 1) {
                s  += __shfl_xor(s,  o, 64);
                s2 += __shfl_xor(s2, o, 64);
            }
            if (lm == 0) { sred[w][ct*4+lg][0] = s; sred[w][ct*4+lg][1] = s2; }
        }
    }
    __syncthreads();
    if (threadIdx.x < 32) {
        int g = threadIdx.x >> 1, k = threadIdx.x & 1;
        float t = sred[0][g][k] + sred[1][g][k] + sred[2][g][k] + sred[3][g][k];
        atomicAdd(&stat[k*16 + g], t);
    }
}

// ---------------- gather (compact) + GN4 + MLP head ----------------
__global__ void k_mlp(const float* __restrict__ pose, const float* __restrict__ sd,
                      const int* __restrict__ pairs, const int* __restrict__ slotmap,
                      const float* __restrict__ compact,
                      const float* __restrict__ g4s, const float* __restrict__ g4b,
                      const float* __restrict__ st4,
                      const float* __restrict__ gw, const float* __restrict__ gb,
                      const float* __restrict__ hw, const float* __restrict__ hb,
                      const float* __restrict__ ow, const float* __restrict__ ob,
                      float* __restrict__ out) {
    int wid  = threadIdx.x >> 6;
    int lane = threadIdx.x & 63;
    int t = blockIdx.x*4 + wid;
    int p = t >> 1;
    const float* pp = pose + t*8;
    float q0=pp[0], q1=pp[1], q2=pp[2], q3=pp[3];
    float f0=pp[4], f1=pp[5], f2=pp[6], tr=pp[7];
    int idx = pairs[2*p];
    float dg = sd[idx];
    float cond[15] = {q0*q0,q0*q1,q0*q2,q0*q3,q1*q1,q1*q2,q1*q3,q2*q2,q2*q3,q3*q3,
                      f0,f1,f2,tr,dg};
    float acc = gb[lane];
    #pragma unroll
    for (int k = 0; k < 15; ++k) acc += cond[k]*gw[k*64+lane];
    float gate = 1.f/(1.f+expf(-acc));
    int slot = slotmap[idx];
    float raw = compact[(size_t)slot*64 + lane];
    int   g4  = lane >> 2;
    float cnt = 4.0f * (float)NN;
    float mu  = st4[g4] / cnt;
    float var = st4[16+g4] / cnt - mu*mu;
    float rs  = rsqrtf(var + 1e-5f);
    float fv  = (raw - mu) * rs * g4s[lane] + g4b[lane];
    float fg  = fv >= 0.f ? fv : 0.2f*fv;
    float h = fg*gate;
    float ss = h*h;
    #pragma unroll
    for (int o = 32; o; o >>= 1) ss += __shfl_xor(ss, o, 64);
    h *= rsqrtf(ss + 1e-8f);
    __shared__ float hs[4][64];
    hs[wid][lane] = h;
    __syncthreads();
    float a2 = hb[lane];
    #pragma unroll 8
    for (int d = 0; d < 64; ++d) a2 += hs[wid][d]*hw[d*64+lane];
    float h2 = a2 >= 0.f ? a2 : 0.2f*a2;
    float si = h2 / (1.f+expf(-h2));
    float v = si * ow[lane];
    #pragma unroll
    for (int o = 32; o; o >>= 1) v += __shfl_xor(v, o, 64);
    if (lane == 0) out[t] = v + ob[0];
}

extern "C" void kernel_launch(void* const* d_in, const int* in_sizes, int n_in,
                              void* d_out, int out_size, void* d_ws, size_t ws_size,
                              hipStream_t stream) {
    const float* depth = (const float*)d_in[0];
    const float* pose  = (const float*)d_in[1];
    const float* mask  = (const float*)d_in[2];
    const int*   pairs = (const int*)  d_in[3];
    const float* c1w = (const float*)d_in[4];  const float* c1b = (const float*)d_in[5];
    const float* g1s = (const float*)d_in[6];  const float* g1b = (const float*)d_in[7];
    const float* c2w = (const float*)d_in[8];  const float* c2b = (const float*)d_in[9];
    const float* g2s = (const float*)d_in[10]; const float* g2b = (const float*)d_in[11];
    const float* c3w = (const float*)d_in[12]; const float* c3b = (const float*)d_in[13];
    const float* g3s = (const float*)d_in[14]; const float* g3b = (const float*)d_in[15];
    const float* c4w = (const float*)d_in[16]; const float* c4b = (const float*)d_in[17];
    const float* g4s = (const float*)d_in[18]; const float* g4b = (const float*)d_in[19];
    const float* gw  = (const float*)d_in[20]; const float* gb  = (const float*)d_in[21];
    const float* hw_ = (const float*)d_in[22]; const float* hb  = (const float*)d_in[23];
    const float* ow  = (const float*)d_in[24]; const float* ob  = (const float*)d_in[25];

    char* base = (char*)d_ws;
    float*  stats = (float*) base;
    float*  X    = (float*) (base + OFF_X);
    ushort* C1R  = (ushort*)(base + OFF_C1R);
    ushort* RW2  = (ushort*)(base + OFF_RW2);
    ushort* RW3  = (ushort*)(base + OFF_RW3);
    ushort* WB2  = (ushort*)(base + OFF_WB2);
    ushort* WB3  = (ushort*)(base + OFF_WB3);
    ushort* WB4  = (ushort*)(base + OFF_WB4);
    int*    SLOT = (int*)   (base + OFF_SLOT);
    float*  CMP  = (float*) (base + OFF_CMP);
    float* st1 = stats + 16;
    float* st2 = stats + 64;
    float* st3 = stats + 112;
    float* st4 = stats + 160;

    hipMemsetAsync(d_ws, 0, 1024, stream);
    hipMemsetAsync(SLOT, 0xFF, (size_t)NN*4, stream);

    k_sum    <<<1024, 256, 0, stream>>>(depth, stats);
    k_buildx <<<(NN+255)/256, 256, 0, stream>>>(depth, mask, stats, X);
    k_scatter<<<(PP+255)/256, 256, 0, stream>>>(pairs, X);
    k_slot   <<<(PP+255)/256, 256, 0, stream>>>(pairs, SLOT);
    k_wcvt   <<< 72, 256, 0, stream>>>(c2w, WB2, 1);
    k_wcvt   <<<144, 256, 0, stream>>>(c3w, WB3, 2);
    k_wcvt   <<<216, 256, 0, stream>>>(c4w, WB4, 3);

    // conv1: 3->32 direct -> raw bf16 + st1
    k_conv1<3,16><<<dim3(10, HH, 2), 64, 0, stream>>>(X, c1w, c1b, C1R, st1);

    // conv2: 32->64 stride2 MFMA (GN1 on stage) -> RW2 raw + st2
    k_sconv<2><<<dim3(10, 60), 256, 0, stream>>>(C1R, nullptr, WB2, c2b,
        g1s, g1b, st1, nullptr, nullptr, nullptr, RW2, nullptr, nullptr, st2);

    // conv3: 64->64 MFMA (GN2 on stage) -> RW3 raw + st3
    k_sconv<3><<<dim3(5, 60), 256, 0, stream>>>(RW2, nullptr, WB3, c3b,
        g2s, g2b, st2, nullptr, nullptr, nullptr, RW3, nullptr, nullptr, st3);

    // conv4: concat(up2(RW3) [GN3], C1R [GN1]) 96->64 MFMA -> compact rows + st4
    k_sconv<4><<<dim3(10, 120), 256, 0, stream>>>(RW3, C1R, WB4, c4b,
        g3s, g3b, st3, g1s, g1b, st1, nullptr, SLOT, CMP, st4);

    // gather + GN4 + MLP head
    k_mlp<<<(2*PP)/4, 256, 0, stream>>>(pose, X, pairs, SLOT, CMP, g4s, g4b, st4,
                                        gw, gb, hw_, hb, ow, ob, (float*)d_out);
}

// Round 8
// 384.233 us; speedup vs baseline: 3.3351x; 3.3351x over previous
//
#include <hip/hip_runtime.h>
#include <math.h>

#define HH 480
#define WW 600
#define NN (HH*WW)      // 288000
#define PP 2048
#define H2 240
#define W2 300
#define N2 (H2*W2)      // 72000

typedef __bf16  bf16x8  __attribute__((ext_vector_type(8)));
typedef float   f32x4   __attribute__((ext_vector_type(4)));
typedef ushort  ushort8 __attribute__((ext_vector_type(8)));

__device__ __forceinline__ ushort f2b(float f) {
    unsigned u = __float_as_uint(f);
    unsigned r = (u + 0x7FFF + ((u >> 16) & 1)) >> 16;
    return (ushort)r;
}
__device__ __forceinline__ float b2f(ushort u) {
    return __uint_as_float(((unsigned)u) << 16);
}

// ---- workspace layout (bytes) ----
// raw (un-normalized) conv outputs stored bf16 [px][C]; GN applied at consumer.
constexpr size_t alup(size_t x) { return (x + 4095) & ~(size_t)4095; }
constexpr size_t OFF_X    = 4096;                          // 3*NN f32 planar
constexpr size_t OFF_C1R  = alup(OFF_X   + 3UL*NN*4);      // NN*32 bf16 raw conv1
constexpr size_t OFF_RW2  = alup(OFF_C1R + 32UL*NN*2);     // N2*64 bf16 raw conv2
constexpr size_t OFF_RW3  = alup(OFF_RW2 + 64UL*N2*2);     // N2*64 bf16 raw conv3
constexpr size_t OFF_WB2  = alup(OFF_RW3 + 64UL*N2*2);     // 9*64*32 bf16
constexpr size_t OFF_WB3  = alup(OFF_WB2 + 36864UL);       // 9*2*64*32 bf16
constexpr size_t OFF_WB4  = alup(OFF_WB3 + 73728UL);       // 9*3*64*32 bf16
constexpr size_t OFF_SLOT = alup(OFF_WB4 + 110592UL);      // NN int
constexpr size_t OFF_CMP  = alup(OFF_SLOT + (size_t)NN*4); // PP*64 f32 compact conv4 rows

// ---------------- depth mean ----------------
__global__ void k_sum(const float* __restrict__ d, float* __restrict__ ws) {
    float s = 0.f;
    for (int i = blockIdx.x*blockDim.x + threadIdx.x; i < NN; i += gridDim.x*blockDim.x)
        s += d[i];
    #pragma unroll
    for (int o = 32; o; o >>= 1) s += __shfl_down(s, o, 64);
    __shared__ float sm[4];
    int wid = threadIdx.x >> 6;
    if ((threadIdx.x & 63) == 0) sm[wid] = s;
    __syncthreads();
    if (threadIdx.x == 0) {
        float t = 0.f;
        for (int w = 0; w < (int)(blockDim.x >> 6); ++w) t += sm[w];
        atomicAdd(ws, t);
    }
}

__global__ void k_buildx(const float* __restrict__ depth, const float* __restrict__ mask,
                         const float* __restrict__ ws, float* __restrict__ x) {
    int i = blockIdx.x*blockDim.x + threadIdx.x;
    if (i >= NN) return;
    float mean = ws[0] * (1.0f/NN);
    x[i]        = (depth[i] - mean) * 10.0f;
    x[NN + i]   = mask[i];
    x[2*NN + i] = 0.f;
}

__global__ void k_scatter(const int* __restrict__ pairs, float* __restrict__ x) {
    int p = blockIdx.x*blockDim.x + threadIdx.x;
    if (p < PP) x[2*NN + pairs[2*p]] = 1.0f;
}

__global__ void k_slot(const int* __restrict__ pairs, int* __restrict__ slotmap) {
    int p = blockIdx.x*blockDim.x + threadIdx.x;
    if (p < PP) slotmap[pairs[2*p]] = p;
}

// ------------- weight pre-transform to MFMA A-fragment layout (bf16) -------------
// dst[((t*NCH + c)*64 + co)*32 + k] = w[co][c*32+k][t]   (t = ky*3+kx)
__global__ void k_wcvt(const float* __restrict__ w, ushort* __restrict__ dst, int NCH) {
    int e = blockIdx.x*256 + threadIdx.x;
    int total = 9*NCH*64*32;
    if (e >= total) return;
    int k  = e & 31;
    int co = (e >> 5) & 63;
    int rest = e >> 11;
    int c = rest % NCH;
    int t = rest / NCH;
    dst[e] = f2b(w[(co*(NCH*32) + c*32 + k)*9 + t]);
}

// ------- conv1: direct 3x3, 3ch fp32 planar -> raw bf16 [px][32] + fused GN1 stats -------
// 8 rows per block (1200 blocks total); stats reduced in-register across rows,
// emitted as ONE wave-parallel atomic instruction (16 lanes) per block.
template<int CIN, int TCO, int YPB>
__global__ __launch_bounds__(64) void k_conv1(const float* __restrict__ in,
        const float* __restrict__ w, const float* __restrict__ bias,
        ushort* __restrict__ outb, float* __restrict__ stat) {
    int x    = blockIdx.x*64 + threadIdx.x;
    int lane = threadIdx.x;
    int co0  = blockIdx.z*TCO;
    bool valid = x < WW;
    float s[TCO/2], s2[TCO/2];
    #pragma unroll
    for (int j = 0; j < TCO/2; ++j) { s[j] = 0.f; s2[j] = 0.f; }

    int  xb   = x - 1;
    bool xint = (xb >= 0) && (xb + 2 < WW);

    for (int yy = 0; yy < YPB; ++yy) {
        int y = blockIdx.y*YPB + yy;
        float acc[TCO];
        #pragma unroll
        for (int c = 0; c < TCO; ++c) acc[c] = bias[co0+c];
        for (int ci = 0; ci < CIN; ++ci) {
            const float* ip = in + (long)ci*NN;
            float iv[3][3];
            #pragma unroll
            for (int dy = 0; dy < 3; ++dy) {
                int iy = y + dy - 1;
                if ((unsigned)iy < (unsigned)HH) {
                    const float* rp = ip + (long)iy*WW + xb;
                    if (xint) { iv[dy][0]=rp[0]; iv[dy][1]=rp[1]; iv[dy][2]=rp[2]; }
                    else {
                        #pragma unroll
                        for (int dx = 0; dx < 3; ++dx) {
                            int ix = xb + dx;
                            iv[dy][dx] = ((unsigned)ix < (unsigned)WW) ? ip[(long)iy*WW+ix] : 0.f;
                        }
                    }
                } else iv[dy][0]=iv[dy][1]=iv[dy][2]=0.f;
            }
            const float* wp = w + ((long)co0*CIN + ci)*9;
            #pragma unroll
            for (int c = 0; c < TCO; ++c)
                #pragma unroll
                for (int k = 0; k < 9; ++k)
                    acc[c] += iv[k/3][k%3] * wp[(long)c*CIN*9 + k];
        }
        if (valid) {
            ushort8 p0, p1;
            #pragma unroll
            for (int j = 0; j < 8; ++j) { p0[j] = f2b(acc[j]); p1[j] = f2b(acc[8+j]); }
            ushort* op = outb + (size_t)(y*WW + x)*32 + co0;
            *(ushort8*)op     = p0;
            *(ushort8*)(op+8) = p1;
            #pragma unroll
            for (int j = 0; j < TCO/2; ++j) {
                float a = acc[2*j], b = acc[2*j+1];
                s[j]  += a + b;
                s2[j] += a*a + b*b;
            }
        }
    }

    // 64-lane butterfly reduce (all lanes end with all 8 group totals)
    #pragma unroll
    for (int o = 1; o < 64; o <<= 1)
        #pragma unroll
        for (int j = 0; j < TCO/2; ++j) {
            s[j]  += __shfl_xor(s[j],  o, 64);
            s2[j] += __shfl_xor(s2[j], o, 64);
        }
    // one wave-parallel atomic instruction: lanes 0..7 -> sums, 8..15 -> sumsqs
    float vs = 0.f, vq = 0.f;
    #pragma unroll
    for (int j = 0; j < TCO/2; ++j) {
        vs = (lane == j)            ? s[j]  : vs;
        vq = (lane == j + TCO/2)    ? s2[j] : vq;
    }
    if (lane < TCO) {
        int g0 = co0 >> 1;
        int addr = (lane < TCO/2) ? (g0 + lane) : (16 + g0 + lane - TCO/2);
        atomicAdd(&stat[addr], (lane < TCO/2) ? vs : vq);
    }
}

// ---------------- LDS-staged MFMA implicit-GEMM 3x3 conv, GN-on-stage ----------------
// Inputs are RAW bf16 [px][C]; staging applies GN (A,B per channel from stats) + lrelu.
// MODE 2: conv2 32->64 s2 (C1 raw -> RW2 raw + st2), tile 4x32
// MODE 3: conv3 64->64    (RW2 raw -> RW3 raw + st3), tile 4x64
// MODE 4: conv4 96->64    (up2x(RW3) ++ C1 raw -> compact rows only + st4), tile 4x64
template<int MODE>
__global__ __launch_bounds__(256) void k_sconv(
        const ushort* __restrict__ inA, const ushort* __restrict__ inB,
        const ushort* __restrict__ wb, const float* __restrict__ bias,
        const float* __restrict__ gsA, const float* __restrict__ gbA, const float* __restrict__ stA,
        const float* __restrict__ gsB, const float* __restrict__ gbB, const float* __restrict__ stB,
        ushort* __restrict__ outb,
        const int* __restrict__ slotmap, float* __restrict__ compact,
        float* __restrict__ stat) {
    constexpr int Wo   = (MODE==4) ? WW : W2;
    constexpr int NCH  = (MODE==2) ? 1 : (MODE==3) ? 2 : 3;
    constexpr int NPT  = (MODE==2) ? 2 : 4;
    constexpr int ROWS = (MODE==2) ? 9 : 6;
    constexpr int PXS  = 68;
    constexpr int CPITCH = 36;
    constexpr int UNITS = ROWS*PXS*4;
    constexpr int Hi = (MODE==3) ? H2 : HH;
    constexpr int Wi = (MODE==3) ? W2 : WW;
    __shared__ __align__(16) ushort sh[ROWS*PXS*CPITCH];
    __shared__ float sred[4][16][2];

    int w    = threadIdx.x >> 6;
    int lane = threadIdx.x & 63;
    int lm   = lane & 15;
    int lg   = lane >> 4;
    int q    = threadIdx.x & 3;           // fixed ci-octet per thread
    int y0   = blockIdx.y*4;
    int x0   = blockIdx.x*(NPT*16);
    int y    = y0 + w;
    int iy0  = (MODE==2) ? 2*y0 : y0 - 1;
    int ix0  = (MODE==2) ? 2*x0 : x0 - 1;

    f32x4 acc[4][NPT];
    #pragma unroll
    for (int ct = 0; ct < 4; ++ct)
        #pragma unroll
        for (int pt = 0; pt < NPT; ++pt) acc[ct][pt] = 0.f;

    int dsbase = (((MODE==2 ? 2*w*PXS + 2*lm : w*PXS + lm))*CPITCH + lg*8);

    #pragma unroll
    for (int kc = 0; kc < NCH; ++kc) {
        if (kc) __syncthreads();
        // ---- per-chunk GN coefficients for this thread's 8 channels ----
        float Ac[8], Bc[8];
        {
            const bool useB = (MODE==4) && (kc == 2);
            const float* gs = useB ? gsB : gsA;
            const float* gb = useB ? gbB : gbA;
            const float* st = useB ? stB : stA;
            const float cnt = (MODE==2 || useB) ? 2.0f*(float)NN : 4.0f*(float)N2;
            const int   shp = (MODE==2 || useB) ? 1 : 2;
            const int   cb  = (MODE==2 || useB) ? q*8 : kc*32 + q*8;
            #pragma unroll
            for (int j = 0; j < 8; ++j) {
                int c = cb + j, g = c >> shp;
                float mu  = st[g] / cnt;
                float var = st[16+g] / cnt - mu*mu;
                float rs  = rsqrtf(var + 1e-5f);
                float a   = rs * gs[c];
                Ac[j] = a; Bc[j] = gb[c] - mu*a;
            }
        }
        // ---- stage chunk kc (raw bf16 -> GN+lrelu -> bf16 LDS) ----
        #pragma unroll
        for (int u0 = 0; u0 < UNITS; u0 += 256) {
            int u = u0 + threadIdx.x;
            if (u < UNITS) {
                int r  = u / (PXS*4);
                int rm = u - r*(PXS*4);
                int px = rm >> 2;
                int iy = iy0 + r;
                int ix = ix0 + px;
                ushort8 pk = {};
                if ((unsigned)iy < (unsigned)Hi && (unsigned)ix < (unsigned)Wi) {
                    const ushort* sp;
                    if (MODE==2)      sp = inA + ((size_t)iy*WW + ix)*32 + q*8;
                    else if (MODE==3) sp = inA + ((size_t)iy*W2 + ix)*64 + kc*32 + q*8;
                    else if (kc < 2)  sp = inA + ((size_t)(iy>>1)*W2 + (ix>>1))*64 + kc*32 + q*8;
                    else              sp = inB + ((size_t)iy*WW + ix)*32 + q*8;
                    ushort8 raw = *(const ushort8*)sp;
                    #pragma unroll
                    for (int j = 0; j < 8; ++j) {
                        float t = b2f(raw[j])*Ac[j] + Bc[j];
                        pk[j] = f2b(t >= 0.f ? t : 0.2f*t);
                    }
                }
                *(ushort8*)&sh[(r*PXS + px)*CPITCH + q*8] = pk;
            }
        }
        __syncthreads();
        // ---- compute chunk kc ----
        #pragma unroll
        for (int t = 0; t < 9; ++t) {
            const int dy = t/3, dx = t - 3*(t/3);
            const ushort* wp = wb + (size_t)((t*NCH + kc)*64)*32;
            bf16x8 a[4];
            #pragma unroll
            for (int ct = 0; ct < 4; ++ct)
                a[ct] = *(const bf16x8*)(wp + (ct*16 + lm)*32 + lg*8);
            #pragma unroll
            for (int pt = 0; pt < NPT; ++pt) {
                int off = (dy*PXS + (MODE==2 ? pt*32 + dx : pt*16 + dx))*CPITCH;
                bf16x8 b = *(const bf16x8*)&sh[dsbase + off];
                #pragma unroll
                for (int ct = 0; ct < 4; ++ct)
                    acc[ct][pt] = __builtin_amdgcn_mfma_f32_16x16x32_bf16(a[ct], b, acc[ct][pt], 0, 0, 0);
            }
        }
    }

    // ---- epilogue ----
    if (MODE != 4) {
        // raw bf16 store [px][64] + fused GN stats (chper=4: group = ct*4+lg)
        #pragma unroll
        for (int ct = 0; ct < 4; ++ct) {
            float s = 0.f, s2 = 0.f;
            #pragma unroll
            for (int pt = 0; pt < NPT; ++pt) {
                int pxg = x0 + pt*16 + lm;
                bool vld = pxg < Wo;
                ushort4 pk;
                #pragma unroll
                for (int reg = 0; reg < 4; ++reg) {
                    int co = ct*16 + lg*4 + reg;
                    float v = acc[ct][pt][reg] + bias[co];
                    ((ushort*)&pk)[reg] = f2b(v);
                    if (vld) { s += v; s2 += v*v; }
                }
                if (vld)
                    *(ushort4*)(outb + (size_t)(y*Wo + pxg)*64 + ct*16 + lg*4) = pk;
            }
            #pragma unroll
            for (int o = 1; o < 16; o <<= 1) {
                s  += __shfl_xor(s,  o, 64);
                s2 += __shfl_xor(s2, o, 64);
            }
            if (lm == 0) { sred[w][ct*4+lg][0] = s; sred[w][ct*4+lg][1] = s2; }
        }
    } else {
        // stats over all px + sparse compact-row store for gathered pixels
        int slots[4];
        #pragma unroll
        for (int pt = 0; pt < 4; ++pt) {
            int pxg = x0 + pt*16 + lm;
            slots[pt] = (pxg < Wo) ? slotmap[(size_t)y*Wo + pxg] : -1;
        }
        #pragma unroll
        for (int ct = 0; ct < 4; ++ct) {
            float s = 0.f, s2 = 0.f;
            #pragma unroll
            for (int pt = 0; pt < 4; ++pt) {
                int pxg = x0 + pt*16 + lm;
                bool vld = pxg < Wo;
                f32x4 r;
                #pragma unroll
                for (int reg = 0; reg < 4; ++reg) {
                    int co = ct*16 + lg*4 + reg;
                    float v = acc[ct][pt][reg] + bias[co];
                    r[reg] = v;
                    if (vld) { s += v; s2 += v*v; }
                }
                if (slots[pt] >= 0)
                    *(f32x4*)(compact + (size_t)slots[pt]*64 + ct*16 + lg*4) = r;
            }
            #pragma unroll
            for (int o = 1; o < 16; o <<= 1) {
                s  += __shfl_xor(s,  o, 64);
                s2 += __shfl_xor(s2, o, 64);
            }
            if (lm == 0) { sred[w][ct*4+lg][0] = s; sred[w][ct*4+lg][1] = s2; }
        }
    }
    __syncthreads();
    if (threadIdx.x < 32) {
        int g = threadIdx.x >> 1, k = threadIdx.x & 1;
        float t = sred[0][g][k] + sred[1][g][k] + sred[2][g][k] + sred[3][g][k];
        atomicAdd(&stat[k*16 + g], t);
    }
}

// ---------------- gather (compact) + GN4 + MLP head ----------------
__global__ void k_mlp(const float* __restrict__ pose, const float* __restrict__ sd,
                      const int* __restrict__ pairs, const int* __restrict__ slotmap,
                      const float* __restrict__ compact,
                      const float* __restrict__ g4s, const float* __restrict__ g4b,
                      const float* __restrict__ st4,
                      const float* __restrict__ gw, const float* __restrict__ gb,
                      const float* __restrict__ hw, const float* __restrict__ hb,
                      const float* __restrict__ ow, const float* __restrict__ ob,
                      float* __restrict__ out) {
    int wid  = threadIdx.x >> 6;
    int lane = threadIdx.x & 63;
    int t = blockIdx.x*4 + wid;
    int p = t >> 1;
    const float* pp = pose + t*8;
    float q0=pp[0], q1=pp[1], q2=pp[2], q3=pp[3];
    float f0=pp[4], f1=pp[5], f2=pp[6], tr=pp[7];
    int idx = pairs[2*p];
    float dg = sd[idx];
    float cond[15] = {q0*q0,q0*q1,q0*q2,q0*q3,q1*q1,q1*q2,q1*q3,q2*q2,q2*q3,q3*q3,
                      f0,f1,f2,tr,dg};
    float acc = gb[lane];
    #pragma unroll
    for (int k = 0; k < 15; ++k) acc += cond[k]*gw[k*64+lane];
    float gate = 1.f/(1.f+expf(-acc));
    int slot = slotmap[idx];
    float raw = compact[(size_t)slot*64 + lane];
    int   g4  = lane >> 2;
    float cnt = 4.0f * (float)NN;
    float mu  = st4[g4] / cnt;
    float var = st4[16+g4] / cnt - mu*mu;
    float rs  = rsqrtf(var + 1e-5f);
    float fv  = (raw - mu) * rs * g4s[lane] + g4b[lane];
    float fg  = fv >= 0.f ? fv : 0.2f*fv;
    float h = fg*gate;
    float ss = h*h;
    #pragma unroll
    for (int o = 32; o; o >>= 1) ss += __shfl_xor(ss, o, 64);
    h *= rsqrtf(ss + 1e-8f);
    __shared__ float hs[4][64];
    hs[wid][lane] = h;
    __syncthreads();
    float a2 = hb[lane];
    #pragma unroll 8
    for (int d = 0; d < 64; ++d) a2 += hs[wid][d]*hw[d*64+lane];
    float h2 = a2 >= 0.f ? a2 : 0.2f*a2;
    float si = h2 / (1.f+expf(-h2));
    float v = si * ow[lane];
    #pragma unroll
    for (int o = 32; o; o >>= 1) v += __shfl_xor(v, o, 64);
    if (lane == 0) out[t] = v + ob[0];
}

extern "C" void kernel_launch(void* const* d_in, const int* in_sizes, int n_in,
                              void* d_out, int out_size, void* d_ws, size_t ws_size,
                              hipStream_t stream) {
    const float* depth = (const float*)d_in[0];
    const float* pose  = (const float*)d_in[1];
    const float* mask  = (const float*)d_in[2];
    const int*   pairs = (const int*)  d_in[3];
    const float* c1w = (const float*)d_in[4];  const float* c1b = (const float*)d_in[5];
    const float* g1s = (const float*)d_in[6];  const float* g1b = (const float*)d_in[7];
    const float* c2w = (const float*)d_in[8];  const float* c2b = (const float*)d_in[9];
    const float* g2s = (const float*)d_in[10]; const float* g2b = (const float*)d_in[11];
    const float* c3w = (const float*)d_in[12]; const float* c3b = (const float*)d_in[13];
    const float* g3s = (const float*)d_in[14]; const float* g3b = (const float*)d_in[15];
    const float* c4w = (const float*)d_in[16]; const float* c4b = (const float*)d_in[17];
    const float* g4s = (const float*)d_in[18]; const float* g4b = (const float*)d_in[19];
    const float* gw  = (const float*)d_in[20]; const float* gb  = (const float*)d_in[21];
    const float* hw_ = (const float*)d_in[22]; const float* hb  = (const float*)d_in[23];
    const float* ow  = (const float*)d_in[24]; const float* ob  = (const float*)d_in[25];

    char* base = (char*)d_ws;
    float*  stats = (float*) base;
    float*  X    = (float*) (base + OFF_X);
    ushort* C1R  = (ushort*)(base + OFF_C1R);
    ushort* RW2  = (ushort*)(base + OFF_RW2);
    ushort* RW3  = (ushort*)(base + OFF_RW3);
    ushort* WB2  = (ushort*)(base + OFF_WB2);
    ushort* WB3  = (ushort*)(base + OFF_WB3);
    ushort* WB4  = (ushort*)(base + OFF_WB4);
    int*    SLOT = (int*)   (base + OFF_SLOT);
    float*  CMP  = (float*) (base + OFF_CMP);
    float* st1 = stats + 16;
    float* st2 = stats + 64;
    float* st3 = stats + 112;
    float* st4 = stats + 160;

    hipMemsetAsync(d_ws, 0, 1024, stream);
    hipMemsetAsync(SLOT, 0xFF, (size_t)NN*4, stream);

    k_sum    <<<1024, 256, 0, stream>>>(depth, stats);
    k_buildx <<<(NN+255)/256, 256, 0, stream>>>(depth, mask, stats, X);
    k_scatter<<<(PP+255)/256, 256, 0, stream>>>(pairs, X);
    k_slot   <<<(PP+255)/256, 256, 0, stream>>>(pairs, SLOT);
    k_wcvt   <<< 72, 256, 0, stream>>>(c2w, WB2, 1);
    k_wcvt   <<<144, 256, 0, stream>>>(c3w, WB3, 2);
    k_wcvt   <<<216, 256, 0, stream>>>(c4w, WB4, 3);

    // conv1: 3->32 direct, 8 rows/block -> raw bf16 + st1 (one wave-parallel atomic/block)
    k_conv1<3,16,8><<<dim3(10, 60, 2), 64, 0, stream>>>(X, c1w, c1b, C1R, st1);

    // conv2: 32->64 stride2 MFMA (GN1 on stage) -> RW2 raw + st2
    k_sconv<2><<<dim3(10, 60), 256, 0, stream>>>(C1R, nullptr, WB2, c2b,
        g1s, g1b, st1, nullptr, nullptr, nullptr, RW2, nullptr, nullptr, st2);

    // conv3: 64->64 MFMA (GN2 on stage) -> RW3 raw + st3
    k_sconv<3><<<dim3(5, 60), 256, 0, stream>>>(RW2, nullptr, WB3, c3b,
        g2s, g2b, st2, nullptr, nullptr, nullptr, RW3, nullptr, nullptr, st3);

    // conv4: concat(up2(RW3) [GN3], C1R [GN1]) 96->64 MFMA -> compact rows + st4
    k_sconv<4><<<dim3(10, 120), 256, 0, stream>>>(RW3, C1R, WB4, c4b,
        g3s, g3b, st3, g1s, g1b, st1, nullptr, SLOT, CMP, st4);

    // gather + GN4 + MLP head
    k_mlp<<<(2*PP)/4, 256, 0, stream>>>(pose, X, pairs, SLOT, CMP, g4s, g4b, st4,
                                        gw, gb, hw_, hb, ow, ob, (float*)d_out);
}

// Round 9
// 316.974 us; speedup vs baseline: 4.0428x; 1.2122x over previous
//
#include <hip/hip_runtime.h>
#include <math.h>

#define HH 480
#define WW 600
#define NN (HH*WW)      // 288000
#define PP 2048
#define H2 240
#define W2 300
#define N2 (H2*W2)      // 72000

typedef __bf16  bf16x8  __attribute__((ext_vector_type(8)));
typedef __bf16  bf16x4  __attribute__((ext_vector_type(4)));
typedef float   f32x4   __attribute__((ext_vector_type(4)));
typedef ushort  ushort8 __attribute__((ext_vector_type(8)));

__device__ __forceinline__ ushort f2b(float f) {
    unsigned u = __float_as_uint(f);
    unsigned r = (u + 0x7FFF + ((u >> 16) & 1)) >> 16;
    return (ushort)r;
}

// ---- workspace layout (bytes) ----
constexpr size_t alup(size_t x) { return (x + 4095) & ~(size_t)4095; }
constexpr size_t OFF_X    = 4096;                          // 3*NN f32 planar
constexpr size_t OFF_C1R  = alup(OFF_X   + 3UL*NN*4);      // NN*32 bf16 raw conv1
constexpr size_t OFF_RW2  = alup(OFF_C1R + 32UL*NN*2);     // N2*64 bf16 raw conv2
constexpr size_t OFF_RW3  = alup(OFF_RW2 + 64UL*N2*2);     // N2*64 bf16 raw conv3
constexpr size_t OFF_WB2  = alup(OFF_RW3 + 64UL*N2*2);     // 9*64*32 bf16
constexpr size_t OFF_WB3  = alup(OFF_WB2 + 36864UL);       // 9*2*64*32 bf16
constexpr size_t OFF_WB4  = alup(OFF_WB3 + 73728UL);       // 9*3*64*32 bf16
constexpr size_t OFF_SLOT = alup(OFF_WB4 + 110592UL);      // NN int
constexpr size_t OFF_CMP  = alup(OFF_SLOT + (size_t)NN*4); // PP*64 f32 compact conv4 rows

// ---------------- depth mean ----------------
__global__ void k_sum(const float* __restrict__ d, float* __restrict__ ws) {
    float s = 0.f;
    for (int i = blockIdx.x*blockDim.x + threadIdx.x; i < NN; i += gridDim.x*blockDim.x)
        s += d[i];
    #pragma unroll
    for (int o = 32; o; o >>= 1) s += __shfl_down(s, o, 64);
    __shared__ float sm[4];
    int wid = threadIdx.x >> 6;
    if ((threadIdx.x & 63) == 0) sm[wid] = s;
    __syncthreads();
    if (threadIdx.x == 0) {
        float t = 0.f;
        for (int w = 0; w < (int)(blockDim.x >> 6); ++w) t += sm[w];
        atomicAdd(ws, t);
    }
}

__global__ void k_buildx(const float* __restrict__ depth, const float* __restrict__ mask,
                         const float* __restrict__ ws, float* __restrict__ x) {
    int i = blockIdx.x*blockDim.x + threadIdx.x;
    if (i >= NN) return;
    float mean = ws[0] * (1.0f/NN);
    x[i]        = (depth[i] - mean) * 10.0f;
    x[NN + i]   = mask[i];
    x[2*NN + i] = 0.f;
}

__global__ void k_scatter(const int* __restrict__ pairs, float* __restrict__ x) {
    int p = blockIdx.x*blockDim.x + threadIdx.x;
    if (p < PP) x[2*NN + pairs[2*p]] = 1.0f;
}

__global__ void k_slot(const int* __restrict__ pairs, int* __restrict__ slotmap) {
    int p = blockIdx.x*blockDim.x + threadIdx.x;
    if (p < PP) slotmap[pairs[2*p]] = p;
}

// ------------- weight pre-transform to MFMA A-fragment layout (bf16) -------------
__global__ void k_wcvt(const float* __restrict__ w, ushort* __restrict__ dst, int NCH) {
    int e = blockIdx.x*256 + threadIdx.x;
    int total = 9*NCH*64*32;
    if (e >= total) return;
    int k  = e & 31;
    int co = (e >> 5) & 63;
    int rest = e >> 11;
    int c = rest % NCH;
    int t = rest / NCH;
    dst[e] = f2b(w[(co*(NCH*32) + c*32 + k)*9 + t]);
}

// ------- conv1: direct 3x3 -> raw bf16 [px][32] + fused GN1 stats -------
template<int CIN, int TCO, int YPB>
__global__ __launch_bounds__(64) void k_conv1(const float* __restrict__ in,
        const float* __restrict__ w, const float* __restrict__ bias,
        ushort* __restrict__ outb, float* __restrict__ stat) {
    int x    = blockIdx.x*64 + threadIdx.x;
    int lane = threadIdx.x;
    int co0  = blockIdx.z*TCO;
    bool valid = x < WW;
    float s[TCO/2], s2[TCO/2];
    #pragma unroll
    for (int j = 0; j < TCO/2; ++j) { s[j] = 0.f; s2[j] = 0.f; }

    int  xb   = x - 1;
    bool xint = (xb >= 0) && (xb + 2 < WW);

    for (int yy = 0; yy < YPB; ++yy) {
        int y = blockIdx.y*YPB + yy;
        float acc[TCO];
        #pragma unroll
        for (int c = 0; c < TCO; ++c) acc[c] = bias[co0+c];
        for (int ci = 0; ci < CIN; ++ci) {
            const float* ip = in + (long)ci*NN;
            float iv[3][3];
            #pragma unroll
            for (int dy = 0; dy < 3; ++dy) {
                int iy = y + dy - 1;
                if ((unsigned)iy < (unsigned)HH) {
                    const float* rp = ip + (long)iy*WW + xb;
                    if (xint) { iv[dy][0]=rp[0]; iv[dy][1]=rp[1]; iv[dy][2]=rp[2]; }
                    else {
                        #pragma unroll
                        for (int dx = 0; dx < 3; ++dx) {
                            int ix = xb + dx;
                            iv[dy][dx] = ((unsigned)ix < (unsigned)WW) ? ip[(long)iy*WW+ix] : 0.f;
                        }
                    }
                } else iv[dy][0]=iv[dy][1]=iv[dy][2]=0.f;
            }
            const float* wp = w + ((long)co0*CIN + ci)*9;
            #pragma unroll
            for (int c = 0; c < TCO; ++c)
                #pragma unroll
                for (int k = 0; k < 9; ++k)
                    acc[c] += iv[k/3][k%3] * wp[(long)c*CIN*9 + k];
        }
        if (valid) {
            bf16x8 p0, p1;
            #pragma unroll
            for (int j = 0; j < 8; ++j) { p0[j] = (__bf16)acc[j]; p1[j] = (__bf16)acc[8+j]; }
            ushort* op = outb + (size_t)(y*WW + x)*32 + co0;
            *(ushort8*)op     = __builtin_bit_cast(ushort8, p0);
            *(ushort8*)(op+8) = __builtin_bit_cast(ushort8, p1);
            #pragma unroll
            for (int j = 0; j < TCO/2; ++j) {
                float a = acc[2*j], b = acc[2*j+1];
                s[j]  += a + b;
                s2[j] += a*a + b*b;
            }
        }
    }

    #pragma unroll
    for (int o = 1; o < 64; o <<= 1)
        #pragma unroll
        for (int j = 0; j < TCO/2; ++j) {
            s[j]  += __shfl_xor(s[j],  o, 64);
            s2[j] += __shfl_xor(s2[j], o, 64);
        }
    float vs = 0.f, vq = 0.f;
    #pragma unroll
    for (int j = 0; j < TCO/2; ++j) {
        vs = (lane == j)         ? s[j]  : vs;
        vq = (lane == j + TCO/2) ? s2[j] : vq;
    }
    if (lane < TCO) {
        int g0 = co0 >> 1;
        int addr = (lane < TCO/2) ? (g0 + lane) : (16 + g0 + lane - TCO/2);
        atomicAdd(&stat[addr], (lane < TCO/2) ? vs : vq);
    }
}

// ---------------- LDS-staged MFMA conv, GN-on-stage + register prefetch (T14) ----------------
// MODE 2: conv2 32->64 s2; MODE 3: conv3 64->64; MODE 4: conv4 96->64 (compact store)
template<int MODE>
__global__ __launch_bounds__(256) void k_sconv(
        const ushort* __restrict__ inA, const ushort* __restrict__ inB,
        const ushort* __restrict__ wb, const float* __restrict__ bias,
        const float* __restrict__ gsA, const float* __restrict__ gbA, const float* __restrict__ stA,
        const float* __restrict__ gsB, const float* __restrict__ gbB, const float* __restrict__ stB,
        ushort* __restrict__ outb,
        const int* __restrict__ slotmap, float* __restrict__ compact,
        float* __restrict__ stat) {
    constexpr int Wo   = (MODE==4) ? WW : W2;
    constexpr int NCH  = (MODE==2) ? 1 : (MODE==3) ? 2 : 3;
    constexpr int NPT  = (MODE==2) ? 2 : 4;
    constexpr int ROWS = (MODE==2) ? 9 : 6;
    constexpr int PXS  = 68;
    constexpr int CPITCH = 36;
    constexpr int UNITS = ROWS*PXS*4;
    constexpr int NLD  = (UNITS + 255)/256;
    constexpr int Hi = (MODE==3) ? H2 : HH;
    constexpr int Wi = (MODE==3) ? W2 : WW;
    __shared__ __align__(16) ushort sh[ROWS*PXS*CPITCH];
    __shared__ float sred[4][16][2];

    int w    = threadIdx.x >> 6;
    int lane = threadIdx.x & 63;
    int lm   = lane & 15;
    int lg   = lane >> 4;
    int q    = threadIdx.x & 3;           // fixed ci-octet per thread
    int y0   = blockIdx.y*4;
    int x0   = blockIdx.x*(NPT*16);
    int y    = y0 + w;
    int iy0  = (MODE==2) ? 2*y0 : y0 - 1;
    int ix0  = (MODE==2) ? 2*x0 : x0 - 1;

    f32x4 acc[4][NPT];
    #pragma unroll
    for (int ct = 0; ct < 4; ++ct)
        #pragma unroll
        for (int pt = 0; pt < NPT; ++pt) acc[ct][pt] = 0.f;

    int dsbase = (((MODE==2 ? 2*w*PXS + 2*lm : w*PXS + lm))*CPITCH + lg*8);

    ushort8  stg[NLD];
    unsigned vmask = 0;

    auto LOADR = [&](int kc) {
        vmask = 0;
        #pragma unroll
        for (int i = 0; i < NLD; ++i) {
            int u = i*256 + (int)threadIdx.x;
            ushort8 v = {};
            if (u < UNITS) {
                int r  = u / (PXS*4);
                int rm = u - r*(PXS*4);
                int px = rm >> 2;
                int iy = iy0 + r;
                int ix = ix0 + px;
                if ((unsigned)iy < (unsigned)Hi && (unsigned)ix < (unsigned)Wi) {
                    const ushort* sp;
                    if (MODE==2)      sp = inA + ((size_t)iy*WW + ix)*32 + q*8;
                    else if (MODE==3) sp = inA + ((size_t)iy*W2 + ix)*64 + kc*32 + q*8;
                    else if (kc < 2)  sp = inA + ((size_t)(iy>>1)*W2 + (ix>>1))*64 + kc*32 + q*8;
                    else              sp = inB + ((size_t)iy*WW + ix)*32 + q*8;
                    v = *(const ushort8*)sp;
                    vmask |= (1u << i);
                }
            }
            stg[i] = v;
        }
    };

    LOADR(0);

    #pragma unroll
    for (int kc = 0; kc < NCH; ++kc) {
        // ---- per-chunk GN coefficients (issued before barrier; latency overlaps) ----
        float Ac[8], Bc[8];
        {
            const bool useB = (MODE==4) && (kc == 2);
            const float* gs = useB ? gsB : gsA;
            const float* gb = useB ? gbB : gbA;
            const float* st = useB ? stB : stA;
            const float cnt = (MODE==2 || useB) ? 2.0f*(float)NN : 4.0f*(float)N2;
            const int   shp = (MODE==2 || useB) ? 1 : 2;
            const int   cb  = (MODE==2 || useB) ? q*8 : kc*32 + q*8;
            #pragma unroll
            for (int j = 0; j < 8; ++j) {
                int c = cb + j, g = c >> shp;
                float mu  = st[g] / cnt;
                float var = st[16+g] / cnt - mu*mu;
                float rs  = rsqrtf(var + 1e-5f);
                float a   = rs * gs[c];
                Ac[j] = a; Bc[j] = gb[c] - mu*a;
            }
        }
        if (kc) __syncthreads();        // previous compute done reading LDS
        // ---- process prefetched regs -> GN+lrelu -> LDS ----
        #pragma unroll
        for (int i = 0; i < NLD; ++i) {
            int u = i*256 + (int)threadIdx.x;
            if (u < UNITS) {
                int r  = u / (PXS*4);
                int rm = u - r*(PXS*4);
                int px = rm >> 2;
                bf16x8 raw = __builtin_bit_cast(bf16x8, stg[i]);
                bool val = (vmask >> i) & 1;
                bf16x8 o;
                #pragma unroll
                for (int j = 0; j < 8; ++j) {
                    float t = (float)raw[j]*Ac[j] + Bc[j];
                    t = fmaxf(t, 0.2f*t);
                    o[j] = (__bf16)(val ? t : 0.f);
                }
                *(ushort8*)&sh[(r*PXS + px)*CPITCH + q*8] = __builtin_bit_cast(ushort8, o);
            }
        }
        __syncthreads();
        if (kc + 1 < NCH) LOADR(kc + 1);   // issue next chunk's loads; wait lands next PROCESS
        // ---- compute chunk kc ----
        #pragma unroll
        for (int t = 0; t < 9; ++t) {
            const int dy = t/3, dx = t - 3*(t/3);
            const ushort* wp = wb + (size_t)((t*NCH + kc)*64)*32;
            bf16x8 a[4];
            #pragma unroll
            for (int ct = 0; ct < 4; ++ct)
                a[ct] = *(const bf16x8*)(wp + (ct*16 + lm)*32 + lg*8);
            #pragma unroll
            for (int pt = 0; pt < NPT; ++pt) {
                int off = (dy*PXS + (MODE==2 ? pt*32 + dx : pt*16 + dx))*CPITCH;
                bf16x8 b = *(const bf16x8*)&sh[dsbase + off];
                #pragma unroll
                for (int ct = 0; ct < 4; ++ct)
                    acc[ct][pt] = __builtin_amdgcn_mfma_f32_16x16x32_bf16(a[ct], b, acc[ct][pt], 0, 0, 0);
            }
        }
    }

    // ---- epilogue ----
    if (MODE != 4) {
        #pragma unroll
        for (int ct = 0; ct < 4; ++ct) {
            float s = 0.f, s2 = 0.f;
            #pragma unroll
            for (int pt = 0; pt < NPT; ++pt) {
                int pxg = x0 + pt*16 + lm;
                bool vld = pxg < Wo;
                bf16x4 pk;
                #pragma unroll
                for (int reg = 0; reg < 4; ++reg) {
                    int co = ct*16 + lg*4 + reg;
                    float v = acc[ct][pt][reg] + bias[co];
                    pk[reg] = (__bf16)v;
                    if (vld) { s += v; s2 += v*v; }
                }
                if (vld)
                    *(bf16x4*)(outb + (size_t)(y*Wo + pxg)*64 + ct*16 + lg*4) = pk;
            }
            #pragma unroll
            for (int o = 1; o < 16; o <<= 1) {
                s  += __shfl_xor(s,  o, 64);
                s2 += __shfl_xor(s2, o, 64);
            }
            if (lm == 0) { sred[w][ct*4+lg][0] = s; sred[w][ct*4+lg][1] = s2; }
        }
    } else {
        int slots[4];
        #pragma unroll
        for (int pt = 0; pt < 4; ++pt) {
            int pxg = x0 + pt*16 + lm;
            slots[pt] = (pxg < Wo) ? slotmap[(size_t)y*Wo + pxg] : -1;
        }
        #pragma unroll
        for (int ct = 0; ct < 4; ++ct) {
            float s = 0.f, s2 = 0.f;
            #pragma unroll
            for (int pt = 0; pt < 4; ++pt) {
                int pxg = x0 + pt*16 + lm;
                bool vld = pxg < Wo;
                f32x4 r;
                #pragma unroll
                for (int reg = 0; reg < 4; ++reg) {
                    int co = ct*16 + lg*4 + reg;
                    float v = acc[ct][pt][reg] + bias[co];
                    r[reg] = v;
                    if (vld) { s += v; s2 += v*v; }
                }
                if (slots[pt] >= 0)
                    *(f32x4*)(compact + (size_t)slots[pt]*64 + ct*16 + lg*4) = r;
            }
            #pragma unroll
            for (int o = 1; o < 16; o <<= 1) {
                s  += __shfl_xor(s,  o, 64);
                s2 += __shfl_xor(s2, o, 64);
            }
            if (lm == 0) { sred[w][ct*4+lg][0] = s; sred[w][ct*4+lg][1] = s2; }
        }
    }
    __syncthreads();
    if (threadIdx.x < 32) {
        int g = threadIdx.x >> 1, k = threadIdx.x & 1;
        float t = sred[0][g][k] + sred[1][g][k] + sred[2][g][k] + sred[3][g][k];
        atomicAdd(&stat[k*16 + g], t);
    }
}

// ---------------- gather (compact) + GN4 + MLP head ----------------
__global__ void k_mlp(const float* __restrict__ pose, const float* __restrict__ sd,
                      const int* __restrict__ pairs, const int* __restrict__ slotmap,
                      const float* __restrict__ compact,
                      const float* __restrict__ g4s, const float* __restrict__ g4b,
                      const float* __restrict__ st4,
                      const float* __restrict__ gw, const float* __restrict__ gb,
                      const float* __restrict__ hw, const float* __restrict__ hb,
                      const float* __restrict__ ow, const float* __restrict__ ob,
                      float* __restrict__ out) {
    int wid  = threadIdx.x >> 6;
    int lane = threadIdx.x & 63;
    int t = blockIdx.x*4 + wid;
    int p = t >> 1;
    const float* pp = pose + t*8;
    float q0=pp[0], q1=pp[1], q2=pp[2], q3=pp[3];
    float f0=pp[4], f1=pp[5], f2=pp[6], tr=pp[7];
    int idx = pairs[2*p];
    float dg = sd[idx];
    float cond[15] = {q0*q0,q0*q1,q0*q2,q0*q3,q1*q1,q1*q2,q1*q3,q2*q2,q2*q3,q3*q3,
                      f0,f1,f2,tr,dg};
    float acc = gb[lane];
    #pragma unroll
    for (int k = 0; k < 15; ++k) acc += cond[k]*gw[k*64+lane];
    float gate = 1.f/(1.f+expf(-acc));
    int slot = slotmap[idx];
    float raw = compact[(size_t)slot*64 + lane];
    int   g4  = lane >> 2;
    float cnt = 4.0f * (float)NN;
    float mu  = st4[g4] / cnt;
    float var = st4[16+g4] / cnt - mu*mu;
    float rs  = rsqrtf(var + 1e-5f);
    float fv  = (raw - mu) * rs * g4s[lane] + g4b[lane];
    float fg  = fv >= 0.f ? fv : 0.2f*fv;
    float h = fg*gate;
    float ss = h*h;
    #pragma unroll
    for (int o = 32; o; o >>= 1) ss += __shfl_xor(ss, o, 64);
    h *= rsqrtf(ss + 1e-8f);
    __shared__ float hs[4][64];
    hs[wid][lane] = h;
    __syncthreads();
    float a2 = hb[lane];
    #pragma unroll 8
    for (int d = 0; d < 64; ++d) a2 += hs[wid][d]*hw[d*64+lane];
    float h2 = a2 >= 0.f ? a2 : 0.2f*a2;
    float si = h2 / (1.f+expf(-h2));
    float v = si * ow[lane];
    #pragma unroll
    for (int o = 32; o; o >>= 1) v += __shfl_xor(v, o, 64);
    if (lane == 0) out[t] = v + ob[0];
}

extern "C" void kernel_launch(void* const* d_in, const int* in_sizes, int n_in,
                              void* d_out, int out_size, void* d_ws, size_t ws_size,
                              hipStream_t stream) {
    const float* depth = (const float*)d_in[0];
    const float* pose  = (const float*)d_in[1];
    const float* mask  = (const float*)d_in[2];
    const int*   pairs = (const int*)  d_in[3];
    const float* c1w = (const float*)d_in[4];  const float* c1b = (const float*)d_in[5];
    const float* g1s = (const float*)d_in[6];  const float* g1b = (const float*)d_in[7];
    const float* c2w = (const float*)d_in[8];  const float* c2b = (const float*)d_in[9];
    const float* g2s = (const float*)d_in[10]; const float* g2b = (const float*)d_in[11];
    const float* c3w = (const float*)d_in[12]; const float* c3b = (const float*)d_in[13];
    const float* g3s = (const float*)d_in[14]; const float* g3b = (const float*)d_in[15];
    const float* c4w = (const float*)d_in[16]; const float* c4b = (const float*)d_in[17];
    const float* g4s = (const float*)d_in[18]; const float* g4b = (const float*)d_in[19];
    const float* gw  = (const float*)d_in[20]; const float* gb  = (const float*)d_in[21];
    const float* hw_ = (const float*)d_in[22]; const float* hb  = (const float*)d_in[23];
    const float* ow  = (const float*)d_in[24]; const float* ob  = (const float*)d_in[25];

    char* base = (char*)d_ws;
    float*  stats = (float*) base;
    float*  X    = (float*) (base + OFF_X);
    ushort* C1R  = (ushort*)(base + OFF_C1R);
    ushort* RW2  = (ushort*)(base + OFF_RW2);
    ushort* RW3  = (ushort*)(base + OFF_RW3);
    ushort* WB2  = (ushort*)(base + OFF_WB2);
    ushort* WB3  = (ushort*)(base + OFF_WB3);
    ushort* WB4  = (ushort*)(base + OFF_WB4);
    int*    SLOT = (int*)   (base + OFF_SLOT);
    float*  CMP  = (float*) (base + OFF_CMP);
    float* st1 = stats + 16;
    float* st2 = stats + 64;
    float* st3 = stats + 112;
    float* st4 = stats + 160;

    hipMemsetAsync(d_ws, 0, 1024, stream);
    hipMemsetAsync(SLOT, 0xFF, (size_t)NN*4, stream);

    k_sum    <<<1024, 256, 0, stream>>>(depth, stats);
    k_buildx <<<(NN+255)/256, 256, 0, stream>>>(depth, mask, stats, X);
    k_scatter<<<(PP+255)/256, 256, 0, stream>>>(pairs, X);
    k_slot   <<<(PP+255)/256, 256, 0, stream>>>(pairs, SLOT);
    k_wcvt   <<< 72, 256, 0, stream>>>(c2w, WB2, 1);
    k_wcvt   <<<144, 256, 0, stream>>>(c3w, WB3, 2);
    k_wcvt   <<<216, 256, 0, stream>>>(c4w, WB4, 3);

    // conv1: 3->32 direct, 8 rows/block -> raw bf16 + st1
    k_conv1<3,16,8><<<dim3(10, 60, 2), 64, 0, stream>>>(X, c1w, c1b, C1R, st1);

    // conv2: 32->64 stride2 MFMA (GN1 on stage) -> RW2 raw + st2
    k_sconv<2><<<dim3(10, 60), 256, 0, stream>>>(C1R, nullptr, WB2, c2b,
        g1s, g1b, st1, nullptr, nullptr, nullptr, RW2, nullptr, nullptr, st2);

    // conv3: 64->64 MFMA (GN2 on stage) -> RW3 raw + st3
    k_sconv<3><<<dim3(5, 60), 256, 0, stream>>>(RW2, nullptr, WB3, c3b,
        g2s, g2b, st2, nullptr, nullptr, nullptr, RW3, nullptr, nullptr, st3);

    // conv4: concat(up2(RW3) [GN3], C1R [GN1]) 96->64 MFMA -> compact rows + st4
    k_sconv<4><<<dim3(10, 120), 256, 0, stream>>>(RW3, C1R, WB4, c4b,
        g3s, g3b, st3, g1s, g1b, st1, nullptr, SLOT, CMP, st4);

    // gather + GN4 + MLP head
    k_mlp<<<(2*PP)/4, 256, 0, stream>>>(pose, X, pairs, SLOT, CMP, g4s, g4b, st4,
                                        gw, gb, hw_, hb, ow, ob, (float*)d_out);
}